// Round 1
// baseline (4129.022 us; speedup 1.0000x reference)
//
#include <hip/hip_runtime.h>

constexpr int TPB = 256;

// ---------------------------------------------------------------- degree/count
__global__ void k_degcnt(const int* __restrict__ ei, int E,
                         int* __restrict__ deg_row, int* __restrict__ cnt_col) {
    int e = blockIdx.x * blockDim.x + threadIdx.x;
    if (e >= E) return;
    atomicAdd(&deg_row[ei[e]], 1);       // deg over row (source)
    atomicAdd(&cnt_col[ei[E + e]], 1);   // in-count over col (target), for mean
}

__global__ void k_dis(const int* __restrict__ deg, float* __restrict__ dis, int N) {
    int i = blockIdx.x * blockDim.x + threadIdx.x;
    if (i >= N) return;
    int d = deg[i];
    dis[i] = (d > 0) ? rsqrtf((float)d) : 0.0f;
}

// ---------------------------------------------------------------- edge pass L1
// acc1[col] += norm * concat(x[row] (3), edge_attr (2))
__global__ void k_edge1(const int* __restrict__ ei, const float* __restrict__ x,
                        const float* __restrict__ ea, const float* __restrict__ dis,
                        float* __restrict__ acc, int E) {
    int e = blockIdx.x * blockDim.x + threadIdx.x;
    if (e >= E) return;
    int r = ei[e], c = ei[E + e];
    float nrm = dis[r] * dis[c];
    if (nrm == 0.0f) return;            // adding zero: skip atomics
    const float* xr = x + 3 * (long)r;
    float x0 = xr[0], x1 = xr[1], x2 = xr[2];
    float2 ev = ((const float2*)ea)[e];
    float* a = acc + 5 * (long)c;
    unsafeAtomicAdd(a + 0, nrm * x0);
    unsafeAtomicAdd(a + 1, nrm * x1);
    unsafeAtomicAdd(a + 2, nrm * x2);
    unsafeAtomicAdd(a + 3, nrm * ev.x);
    unsafeAtomicAdd(a + 4, nrm * ev.y);
}

// ---------------------------------------------------------------- node pass L1
// h = relu(x@Wc1 + bc1 + (acc1/max(cnt,1))@Wn1)
__global__ void k_node1(const float* __restrict__ x, const float* __restrict__ acc,
                        const int* __restrict__ cnt,
                        const float* __restrict__ Wc, const float* __restrict__ bc,
                        const float* __restrict__ Wn,
                        float* __restrict__ h, int N) {
    __shared__ float sWc[3 * 16], sbc[16], sWn[5 * 16];
    for (int t = threadIdx.x; t < 48; t += blockDim.x) sWc[t] = Wc[t];
    for (int t = threadIdx.x; t < 16; t += blockDim.x) sbc[t] = bc[t];
    for (int t = threadIdx.x; t < 80; t += blockDim.x) sWn[t] = Wn[t];
    __syncthreads();
    int i = blockIdx.x * blockDim.x + threadIdx.x;
    if (i >= N) return;
    float inv = 1.0f / fmaxf((float)cnt[i], 1.0f);
    float m[5];
#pragma unroll
    for (int j = 0; j < 5; j++) m[j] = acc[5 * (long)i + j] * inv;
    float xv[3];
#pragma unroll
    for (int j = 0; j < 3; j++) xv[j] = x[3 * (long)i + j];
    float o[16];
#pragma unroll
    for (int k = 0; k < 16; k++) {
        float v = sbc[k];
#pragma unroll
        for (int j = 0; j < 3; j++) v += xv[j] * sWc[j * 16 + k];
#pragma unroll
        for (int j = 0; j < 5; j++) v += m[j] * sWn[j * 16 + k];
        o[k] = fmaxf(v, 0.0f);
    }
    float4* hp = (float4*)(h + 16 * (long)i);
#pragma unroll
    for (int q = 0; q < 4; q++)
        hp[q] = make_float4(o[4 * q], o[4 * q + 1], o[4 * q + 2], o[4 * q + 3]);
}

// ---------------------------------------------------------------- edge pass L2
// acc2[col] += norm * concat(h[row] (16), edge_attr (2))
__global__ void k_edge2(const int* __restrict__ ei, const float* __restrict__ h,
                        const float* __restrict__ ea, const float* __restrict__ dis,
                        float* __restrict__ acc, int E) {
    int e = blockIdx.x * blockDim.x + threadIdx.x;
    if (e >= E) return;
    int r = ei[e], c = ei[E + e];
    float nrm = dis[r] * dis[c];
    if (nrm == 0.0f) return;
    const float4* hr = (const float4*)(h + 16 * (long)r);
    float4 h0 = hr[0], h1 = hr[1], h2 = hr[2], h3 = hr[3];
    float2 ev = ((const float2*)ea)[e];
    float* a = acc + 18 * (long)c;
    unsafeAtomicAdd(a + 0,  nrm * h0.x);
    unsafeAtomicAdd(a + 1,  nrm * h0.y);
    unsafeAtomicAdd(a + 2,  nrm * h0.z);
    unsafeAtomicAdd(a + 3,  nrm * h0.w);
    unsafeAtomicAdd(a + 4,  nrm * h1.x);
    unsafeAtomicAdd(a + 5,  nrm * h1.y);
    unsafeAtomicAdd(a + 6,  nrm * h1.z);
    unsafeAtomicAdd(a + 7,  nrm * h1.w);
    unsafeAtomicAdd(a + 8,  nrm * h2.x);
    unsafeAtomicAdd(a + 9,  nrm * h2.y);
    unsafeAtomicAdd(a + 10, nrm * h2.z);
    unsafeAtomicAdd(a + 11, nrm * h2.w);
    unsafeAtomicAdd(a + 12, nrm * h3.x);
    unsafeAtomicAdd(a + 13, nrm * h3.y);
    unsafeAtomicAdd(a + 14, nrm * h3.z);
    unsafeAtomicAdd(a + 15, nrm * h3.w);
    unsafeAtomicAdd(a + 16, nrm * ev.x);
    unsafeAtomicAdd(a + 17, nrm * ev.y);
}

// ------------------------------------------------------- node pass L2 + pooling
// h2 = relu(h@Wc2 + bc2 + (acc2/cnt)@Wn2); pool[batch] += h2 (LDS-staged)
__global__ void k_node2(const float* __restrict__ h, const float* __restrict__ acc,
                        const int* __restrict__ cnt, const int* __restrict__ batch,
                        const float* __restrict__ Wc, const float* __restrict__ bc,
                        const float* __restrict__ Wn,
                        float* __restrict__ pool, int* __restrict__ poolcnt, int N) {
    __shared__ float sWc[16 * 16], sbc[16], sWn[18 * 16];
    __shared__ float sp[64 * 16];
    __shared__ int   sc[64];
    for (int t = threadIdx.x; t < 256; t += blockDim.x) sWc[t] = Wc[t];
    for (int t = threadIdx.x; t < 16;  t += blockDim.x) sbc[t] = bc[t];
    for (int t = threadIdx.x; t < 288; t += blockDim.x) sWn[t] = Wn[t];
    for (int t = threadIdx.x; t < 1024; t += blockDim.x) sp[t] = 0.0f;
    for (int t = threadIdx.x; t < 64;  t += blockDim.x) sc[t] = 0;
    __syncthreads();
    int i = blockIdx.x * blockDim.x + threadIdx.x;
    if (i < N) {
        float inv = 1.0f / fmaxf((float)cnt[i], 1.0f);
        float m[18];
#pragma unroll
        for (int j = 0; j < 18; j++) m[j] = acc[18 * (long)i + j] * inv;
        float hv[16];
        const float4* hp = (const float4*)(h + 16 * (long)i);
#pragma unroll
        for (int q = 0; q < 4; q++) {
            float4 t4 = hp[q];
            hv[4 * q] = t4.x; hv[4 * q + 1] = t4.y;
            hv[4 * q + 2] = t4.z; hv[4 * q + 3] = t4.w;
        }
        int b = batch[i];
        atomicAdd(&sc[b], 1);
#pragma unroll
        for (int k = 0; k < 16; k++) {
            float v = sbc[k];
#pragma unroll
            for (int j = 0; j < 16; j++) v += hv[j] * sWc[j * 16 + k];
#pragma unroll
            for (int j = 0; j < 18; j++) v += m[j] * sWn[j * 16 + k];
            v = fmaxf(v, 0.0f);
            unsafeAtomicAdd(&sp[b * 16 + k], v);
        }
    }
    __syncthreads();
    for (int t = threadIdx.x; t < 1024; t += blockDim.x)
        if (sp[t] != 0.0f) unsafeAtomicAdd(&pool[t], sp[t]);
    for (int t = threadIdx.x; t < 64; t += blockDim.x)
        if (sc[t]) atomicAdd(&poolcnt[t], sc[t]);
}

// ---------------------------------------------------------------- MLP head
__global__ void k_final(const float* __restrict__ pool, const int* __restrict__ poolcnt,
                        const float* __restrict__ Wl1, const float* __restrict__ bl1,
                        const float* __restrict__ Wl2, const float* __restrict__ bl2,
                        float* __restrict__ out) {
    int g = threadIdx.x;
    if (g >= 64) return;
    float inv = 1.0f / fmaxf((float)poolcnt[g], 1.0f);
    float gv[16];
#pragma unroll
    for (int k = 0; k < 16; k++) gv[k] = pool[g * 16 + k] * inv;
    float t[16];
#pragma unroll
    for (int k = 0; k < 16; k++) {
        float v = bl1[k];
#pragma unroll
        for (int j = 0; j < 16; j++) v += gv[j] * Wl1[j * 16 + k];
        t[k] = fmaxf(v, 0.0f);
    }
    float o0 = bl2[0], o1 = bl2[1];
#pragma unroll
    for (int j = 0; j < 16; j++) {
        o0 += t[j] * Wl2[j * 2 + 0];
        o1 += t[j] * Wl2[j * 2 + 1];
    }
    out[2 * g + 0] = o0;
    out[2 * g + 1] = o1;
}

extern "C" void kernel_launch(void* const* d_in, const int* in_sizes, int n_in,
                              void* d_out, int out_size, void* d_ws, size_t ws_size,
                              hipStream_t stream) {
    const float* x     = (const float*)d_in[0];
    const int*   ei    = (const int*)  d_in[1];
    const float* ea    = (const float*)d_in[2];
    const int*   batch = (const int*)  d_in[3];
    const float* Wc1   = (const float*)d_in[4];
    const float* bc1   = (const float*)d_in[5];
    const float* Wn1   = (const float*)d_in[6];
    const float* Wc2   = (const float*)d_in[7];
    const float* bc2   = (const float*)d_in[8];
    const float* Wn2   = (const float*)d_in[9];
    const float* Wl1   = (const float*)d_in[10];
    const float* bl1   = (const float*)d_in[11];
    const float* Wl2   = (const float*)d_in[12];
    const float* bl2   = (const float*)d_in[13];
    float* out = (float*)d_out;

    const int N = in_sizes[0] / 3;
    const int E = in_sizes[1] / 2;

    char* ws = (char*)d_ws;
    size_t o = 0;
    auto alloc = [&](size_t bytes) {
        void* p = ws + o;
        o += (bytes + 255) & ~(size_t)255;
        return p;
    };
    int*   deg_row = (int*)  alloc((size_t)N * 4);
    int*   cnt_col = (int*)  alloc((size_t)N * 4);
    float* acc1    = (float*)alloc((size_t)N * 5 * 4);
    float* acc2    = (float*)alloc((size_t)N * 18 * 4);
    float* pool    = (float*)alloc(64 * 16 * 4);
    int*   poolcnt = (int*)  alloc(64 * 4);
    size_t zbytes = o;                       // everything above must start at 0
    float* dis     = (float*)alloc((size_t)N * 4);
    float* h       = (float*)alloc((size_t)N * 16 * 4);
    (void)ws_size;

    hipMemsetAsync(d_ws, 0, zbytes, stream);

    int gE = (E + TPB - 1) / TPB;
    int gN = (N + TPB - 1) / TPB;
    k_degcnt<<<gE, TPB, 0, stream>>>(ei, E, deg_row, cnt_col);
    k_dis   <<<gN, TPB, 0, stream>>>(deg_row, dis, N);
    k_edge1 <<<gE, TPB, 0, stream>>>(ei, x, ea, dis, acc1, E);
    k_node1 <<<gN, TPB, 0, stream>>>(x, acc1, cnt_col, Wc1, bc1, Wn1, h, N);
    k_edge2 <<<gE, TPB, 0, stream>>>(ei, h, ea, dis, acc2, E);
    k_node2 <<<gN, TPB, 0, stream>>>(h, acc2, cnt_col, batch, Wc2, bc2, Wn2,
                                     pool, poolcnt, N);
    k_final <<<1, 64, 0, stream>>>(pool, poolcnt, Wl1, bl1, Wl2, bl2, out);
}

// Round 2
// 646.267 us; speedup vs baseline: 6.3890x; 6.3890x over previous
//
#include <hip/hip_runtime.h>

constexpr int TPB = 256;

// ---------------------------------------------------------------- degree/count
__global__ void k_degcnt(const int* __restrict__ ei, int E,
                         int* __restrict__ deg_row, int* __restrict__ cnt_col) {
    int e = blockIdx.x * blockDim.x + threadIdx.x;
    if (e >= E) return;
    atomicAdd(&deg_row[ei[e]], 1);       // deg over row (source)
    atomicAdd(&cnt_col[ei[E + e]], 1);   // in-count over col (target), for mean
}

__global__ void k_dis(const int* __restrict__ deg, float* __restrict__ dis, int N) {
    int i = blockIdx.x * blockDim.x + threadIdx.x;
    if (i >= N) return;
    int d = deg[i];
    dis[i] = (d > 0) ? rsqrtf((float)d) : 0.0f;
}

// ---------------------------------------------------------------- scan (3-phase)
__global__ void k_scan1(const int* __restrict__ cnt, int* __restrict__ bsum, int N) {
    __shared__ int s[256];
    int i = blockIdx.x * 256 + threadIdx.x;
    s[threadIdx.x] = (i < N) ? cnt[i] : 0;
    __syncthreads();
    for (int off = 128; off > 0; off >>= 1) {
        if (threadIdx.x < off) s[threadIdx.x] += s[threadIdx.x + off];
        __syncthreads();
    }
    if (threadIdx.x == 0) bsum[blockIdx.x] = s[0];
}

// in-place exclusive scan of bsum[0..NB), single block, chunked
__global__ void k_scan2(int* __restrict__ bsum, int NB) {
    __shared__ int tmp[2][256];
    __shared__ int carry_s;
    int t = threadIdx.x;
    if (t == 0) carry_s = 0;
    __syncthreads();
    for (int chunk = 0; chunk < NB; chunk += 256) {
        int idx = chunk + t;
        int v = (idx < NB) ? bsum[idx] : 0;
        int buf = 0;
        tmp[0][t] = v;
        __syncthreads();
        for (int off = 1; off < 256; off <<= 1) {
            int nv = tmp[buf][t] + ((t >= off) ? tmp[buf][t - off] : 0);
            buf ^= 1;
            tmp[buf][t] = nv;
            __syncthreads();
        }
        int incl = tmp[buf][t];
        int carry = carry_s;            // stable: last write was before prev barrier
        if (idx < NB) bsum[idx] = carry + incl - v;   // exclusive + carry
        __syncthreads();
        if (t == 255) carry_s = carry + incl;
        __syncthreads();
    }
}

__global__ void k_scan3(const int* __restrict__ cnt, const int* __restrict__ bsum,
                        int* __restrict__ base, int N) {
    __shared__ int tmp[2][256];
    int t = threadIdx.x;
    int i = blockIdx.x * 256 + t;
    int v = (i < N) ? cnt[i] : 0;
    int buf = 0;
    tmp[0][t] = v;
    __syncthreads();
    for (int off = 1; off < 256; off <<= 1) {
        int nv = tmp[buf][t] + ((t >= off) ? tmp[buf][t - off] : 0);
        buf ^= 1;
        tmp[buf][t] = nv;
        __syncthreads();
    }
    int incl = tmp[buf][t];
    if (i < N) base[i] = bsum[blockIdx.x] + incl - v;  // global exclusive prefix
}

// ---------------------------------------------------------------- CSR scatter
// rec[pos] = {row, nrm, nrm*ea.x, nrm*ea.y}; shared by both layers
__global__ void k_scatter(const int* __restrict__ ei, const float* __restrict__ ea,
                          const float* __restrict__ dis, const int* __restrict__ base,
                          int* __restrict__ fill, int4* __restrict__ rec, int E) {
    int e = blockIdx.x * blockDim.x + threadIdx.x;
    if (e >= E) return;
    int r = ei[e], c = ei[E + e];
    float nrm = dis[r] * dis[c];
    float2 ev = ((const float2*)ea)[e];
    int pos = base[c] + atomicAdd(&fill[c], 1);
    int4 rv;
    rv.x = r;
    rv.y = __float_as_int(nrm);
    rv.z = __float_as_int(nrm * ev.x);
    rv.w = __float_as_int(nrm * ev.y);
    rec[pos] = rv;
}

// ------------------------------------------- gather L1 + node update (fused)
// h = relu(x@Wc1 + bc1 + (sum_e nrm*[x_r,ea] / cnt)@Wn1)
__global__ void k_gather1(const float* __restrict__ x, const int4* __restrict__ rec,
                          const int* __restrict__ base, const int* __restrict__ cnt,
                          const float* __restrict__ Wc, const float* __restrict__ bc,
                          const float* __restrict__ Wn,
                          float* __restrict__ h, int N) {
    __shared__ float sWc[3 * 16], sbc[16], sWn[5 * 16];
    for (int t = threadIdx.x; t < 48; t += blockDim.x) sWc[t] = Wc[t];
    for (int t = threadIdx.x; t < 16; t += blockDim.x) sbc[t] = bc[t];
    for (int t = threadIdx.x; t < 80; t += blockDim.x) sWn[t] = Wn[t];
    __syncthreads();
    int i = blockIdx.x * blockDim.x + threadIdx.x;
    if (i >= N) return;
    int b0 = base[i], dg = cnt[i];
    float a0 = 0, a1 = 0, a2 = 0, a3 = 0, a4 = 0;
    for (int k = 0; k < dg; k++) {
        int4 rv = rec[b0 + k];
        float nrm = __int_as_float(rv.y);
        const float* xr = x + 3 * (long)rv.x;
        a0 += nrm * xr[0];
        a1 += nrm * xr[1];
        a2 += nrm * xr[2];
        a3 += __int_as_float(rv.z);
        a4 += __int_as_float(rv.w);
    }
    float inv = 1.0f / fmaxf((float)dg, 1.0f);
    float m[5] = {a0 * inv, a1 * inv, a2 * inv, a3 * inv, a4 * inv};
    float xv[3];
#pragma unroll
    for (int j = 0; j < 3; j++) xv[j] = x[3 * (long)i + j];
    float o[16];
#pragma unroll
    for (int k = 0; k < 16; k++) {
        float v = sbc[k];
#pragma unroll
        for (int j = 0; j < 3; j++) v += xv[j] * sWc[j * 16 + k];
#pragma unroll
        for (int j = 0; j < 5; j++) v += m[j] * sWn[j * 16 + k];
        o[k] = fmaxf(v, 0.0f);
    }
    float4* hp = (float4*)(h + 16 * (long)i);
#pragma unroll
    for (int q = 0; q < 4; q++)
        hp[q] = make_float4(o[4 * q], o[4 * q + 1], o[4 * q + 2], o[4 * q + 3]);
}

// ------------------------------- gather L2 + node update + pooling (fused)
__global__ void k_gather2(const float* __restrict__ h, const int4* __restrict__ rec,
                          const int* __restrict__ base, const int* __restrict__ cnt,
                          const int* __restrict__ batch,
                          const float* __restrict__ Wc, const float* __restrict__ bc,
                          const float* __restrict__ Wn,
                          float* __restrict__ pool, int* __restrict__ poolcnt, int N) {
    __shared__ float sWc[16 * 16], sbc[16], sWn[18 * 16];
    __shared__ float sp[64 * 16];
    __shared__ int   sc[64];
    for (int t = threadIdx.x; t < 256; t += blockDim.x) sWc[t] = Wc[t];
    for (int t = threadIdx.x; t < 16;  t += blockDim.x) sbc[t] = bc[t];
    for (int t = threadIdx.x; t < 288; t += blockDim.x) sWn[t] = Wn[t];
    for (int t = threadIdx.x; t < 1024; t += blockDim.x) sp[t] = 0.0f;
    for (int t = threadIdx.x; t < 64;  t += blockDim.x) sc[t] = 0;
    __syncthreads();
    int i = blockIdx.x * blockDim.x + threadIdx.x;
    if (i < N) {
        int b0 = base[i], dg = cnt[i];
        float m[18];
#pragma unroll
        for (int j = 0; j < 18; j++) m[j] = 0.0f;
        for (int k = 0; k < dg; k++) {
            int4 rv = rec[b0 + k];
            float nrm = __int_as_float(rv.y);
            const float4* hr = (const float4*)(h + 16 * (long)rv.x);
            float4 h0 = hr[0], h1 = hr[1], h2 = hr[2], h3 = hr[3];
            m[0]  += nrm * h0.x;  m[1]  += nrm * h0.y;
            m[2]  += nrm * h0.z;  m[3]  += nrm * h0.w;
            m[4]  += nrm * h1.x;  m[5]  += nrm * h1.y;
            m[6]  += nrm * h1.z;  m[7]  += nrm * h1.w;
            m[8]  += nrm * h2.x;  m[9]  += nrm * h2.y;
            m[10] += nrm * h2.z;  m[11] += nrm * h2.w;
            m[12] += nrm * h3.x;  m[13] += nrm * h3.y;
            m[14] += nrm * h3.z;  m[15] += nrm * h3.w;
            m[16] += __int_as_float(rv.z);
            m[17] += __int_as_float(rv.w);
        }
        float inv = 1.0f / fmaxf((float)dg, 1.0f);
#pragma unroll
        for (int j = 0; j < 18; j++) m[j] *= inv;
        float hv[16];
        const float4* hp = (const float4*)(h + 16 * (long)i);
#pragma unroll
        for (int q = 0; q < 4; q++) {
            float4 t4 = hp[q];
            hv[4 * q] = t4.x; hv[4 * q + 1] = t4.y;
            hv[4 * q + 2] = t4.z; hv[4 * q + 3] = t4.w;
        }
        int b = batch[i];
        atomicAdd(&sc[b], 1);
#pragma unroll
        for (int k = 0; k < 16; k++) {
            float v = sbc[k];
#pragma unroll
            for (int j = 0; j < 16; j++) v += hv[j] * sWc[j * 16 + k];
#pragma unroll
            for (int j = 0; j < 18; j++) v += m[j] * sWn[j * 16 + k];
            v = fmaxf(v, 0.0f);
            unsafeAtomicAdd(&sp[b * 16 + k], v);
        }
    }
    __syncthreads();
    for (int t = threadIdx.x; t < 1024; t += blockDim.x)
        if (sp[t] != 0.0f) unsafeAtomicAdd(&pool[t], sp[t]);
    for (int t = threadIdx.x; t < 64; t += blockDim.x)
        if (sc[t]) atomicAdd(&poolcnt[t], sc[t]);
}

// ---------------------------------------------------------------- MLP head
__global__ void k_final(const float* __restrict__ pool, const int* __restrict__ poolcnt,
                        const float* __restrict__ Wl1, const float* __restrict__ bl1,
                        const float* __restrict__ Wl2, const float* __restrict__ bl2,
                        float* __restrict__ out) {
    int g = threadIdx.x;
    if (g >= 64) return;
    float inv = 1.0f / fmaxf((float)poolcnt[g], 1.0f);
    float gv[16];
#pragma unroll
    for (int k = 0; k < 16; k++) gv[k] = pool[g * 16 + k] * inv;
    float t[16];
#pragma unroll
    for (int k = 0; k < 16; k++) {
        float v = bl1[k];
#pragma unroll
        for (int j = 0; j < 16; j++) v += gv[j] * Wl1[j * 16 + k];
        t[k] = fmaxf(v, 0.0f);
    }
    float o0 = bl2[0], o1 = bl2[1];
#pragma unroll
    for (int j = 0; j < 16; j++) {
        o0 += t[j] * Wl2[j * 2 + 0];
        o1 += t[j] * Wl2[j * 2 + 1];
    }
    out[2 * g + 0] = o0;
    out[2 * g + 1] = o1;
}

extern "C" void kernel_launch(void* const* d_in, const int* in_sizes, int n_in,
                              void* d_out, int out_size, void* d_ws, size_t ws_size,
                              hipStream_t stream) {
    const float* x     = (const float*)d_in[0];
    const int*   ei    = (const int*)  d_in[1];
    const float* ea    = (const float*)d_in[2];
    const int*   batch = (const int*)  d_in[3];
    const float* Wc1   = (const float*)d_in[4];
    const float* bc1   = (const float*)d_in[5];
    const float* Wn1   = (const float*)d_in[6];
    const float* Wc2   = (const float*)d_in[7];
    const float* bc2   = (const float*)d_in[8];
    const float* Wn2   = (const float*)d_in[9];
    const float* Wl1   = (const float*)d_in[10];
    const float* bl1   = (const float*)d_in[11];
    const float* Wl2   = (const float*)d_in[12];
    const float* bl2   = (const float*)d_in[13];
    float* out = (float*)d_out;

    const int N = in_sizes[0] / 3;
    const int E = in_sizes[1] / 2;
    const int NB = (N + 255) / 256;

    char* ws = (char*)d_ws;
    size_t o = 0;
    auto alloc = [&](size_t bytes) {
        void* p = ws + o;
        o += (bytes + 255) & ~(size_t)255;
        return p;
    };
    // zeroed region first
    int*   deg_row = (int*)  alloc((size_t)N * 4);
    int*   cnt_col = (int*)  alloc((size_t)N * 4);
    int*   fill    = (int*)  alloc((size_t)N * 4);
    float* pool    = (float*)alloc(64 * 16 * 4);
    int*   poolcnt = (int*)  alloc(64 * 4);
    size_t zbytes = o;
    // non-zeroed
    float* dis     = (float*)alloc((size_t)N * 4);
    int*   base    = (int*)  alloc((size_t)N * 4);
    int*   bsum    = (int*)  alloc((size_t)NB * 4);
    int4*  rec     = (int4*) alloc((size_t)E * 16);
    float* h       = (float*)alloc((size_t)N * 16 * 4);
    (void)ws_size;

    hipMemsetAsync(d_ws, 0, zbytes, stream);

    int gE = (E + TPB - 1) / TPB;
    int gN = (N + TPB - 1) / TPB;
    k_degcnt <<<gE, TPB, 0, stream>>>(ei, E, deg_row, cnt_col);
    k_dis    <<<gN, TPB, 0, stream>>>(deg_row, dis, N);
    k_scan1  <<<NB, 256, 0, stream>>>(cnt_col, bsum, N);
    k_scan2  <<<1, 256, 0, stream>>>(bsum, NB);
    k_scan3  <<<NB, 256, 0, stream>>>(cnt_col, bsum, base, N);
    k_scatter<<<gE, TPB, 0, stream>>>(ei, ea, dis, base, fill, rec, E);
    k_gather1<<<gN, TPB, 0, stream>>>(x, rec, base, cnt_col, Wc1, bc1, Wn1, h, N);
    k_gather2<<<gN, TPB, 0, stream>>>(h, rec, base, cnt_col, batch, Wc2, bc2, Wn2,
                                      pool, poolcnt, N);
    k_final  <<<1, 64, 0, stream>>>(pool, poolcnt, Wl1, bl1, Wl2, bl2, out);
}